// Round 8
// baseline (173.900 us; speedup 1.0000x reference)
//
#include <hip/hip_runtime.h>

#define LRELU_ALPHA 0.2f

typedef __bf16 bf16x8 __attribute__((ext_vector_type(8)));
typedef unsigned short u16;
typedef unsigned short u16x8 __attribute__((ext_vector_type(8)));
typedef float f32x4 __attribute__((ext_vector_type(4)));
typedef int int4v __attribute__((ext_vector_type(4)));
typedef unsigned int u32;
typedef unsigned long long u64;

__device__ __forceinline__ u16 f2bf(float f) {
  unsigned int u = __float_as_uint(f);
  u += 0x7fffu + ((u >> 16) & 1u);   // RNE
  return (u16)(u >> 16);
}

// async global->LDS, 16B per active lane; dest = wave-uniform base + lane*16
__device__ __forceinline__ void gload16(const void* g, void* lds) {
  __builtin_amdgcn_global_load_lds(
      (const __attribute__((address_space(1))) void*)g,
      (__attribute__((address_space(3))) void*)lds, 16, 0, 0);
}

// ------- kernel 1: packadj (blocks 0..4095) + wcast (blocks 4096..4351) ----
__global__ __launch_bounds__(256) void packw(const int* __restrict__ adj,
                                             u32* __restrict__ maskg,
                                             const float* __restrict__ W,
                                             u16* __restrict__ WbT) {
  const int tid = threadIdx.x;
  if (blockIdx.x >= 4096) {
    int idx = (blockIdx.x - 4096) * 256 + tid;        // 65536
    WbT[idx] = f2bf(W[(idx & 255) * 256 + (idx >> 8)]);
    return;
  }
  const int l = tid & 63, w = tid >> 6;
  const size_t row = (size_t)blockIdx.x * 4 + w;
  const int* arow = adj + row * 4096;
  u64* mrow = (u64*)(maskg + row * 128);
  for (int it = 0; it < 16; ++it) {
    const int* base = arow + it * 256;
    int v0 = base[l], v1 = base[l + 64], v2 = base[l + 128], v3 = base[l + 192];
    u64 b0 = __ballot(v0 != 0);
    u64 b1 = __ballot(v1 != 0);
    u64 b2 = __ballot(v2 != 0);
    u64 b3 = __ballot(v3 != 0);
    if (l == 0) {
      mrow[it * 4 + 0] = b0;
      mrow[it * 4 + 1] = b1;
      mrow[it * 4 + 2] = b2;
      mrow[it * 4 + 3] = b3;
    }
  }
}

// ---------------- kernel 2: Hh = bf16(h) @ W, fused s/d dots ----------
// HhTt tiled layout (u16 index):
// b*1048576 + (k>>5)*8192 + (col>>4)*512 + ((k>>3)&3)*128 + (col&15)*8 + (k&7)
__global__ __launch_bounds__(256) void gemm1(const float* __restrict__ h,
                                             const u16* __restrict__ WbT,
                                             const float* __restrict__ a,
                                             u16* __restrict__ HhTt,
                                             float* __restrict__ sbuf,
                                             float* __restrict__ dbuf) {
  const int tid = threadIdx.x, bid = blockIdx.x;
  const int l = tid & 63, w = tid >> 6;
  const int lr = l & 15;
  const int lk = (l >> 4) << 3;
  const int rowA = bid * 64 + 16 * w + lr;
  const float* hrow = h + (size_t)rowA * 256 + lk;

  f32x4 acc[16];
#pragma unroll
  for (int n = 0; n < 16; ++n) acc[n] = (f32x4){0.f, 0.f, 0.f, 0.f};

  for (int k0 = 0; k0 < 256; k0 += 32) {
    f32x4 a0 = *(const f32x4*)(hrow + k0);
    f32x4 a1 = *(const f32x4*)(hrow + k0 + 4);
    u16x8 au;
    au[0] = f2bf(a0[0]); au[1] = f2bf(a0[1]); au[2] = f2bf(a0[2]); au[3] = f2bf(a0[3]);
    au[4] = f2bf(a1[0]); au[5] = f2bf(a1[1]); au[6] = f2bf(a1[2]); au[7] = f2bf(a1[3]);
    bf16x8 af = __builtin_bit_cast(bf16x8, au);
#pragma unroll
    for (int n = 0; n < 16; ++n) {
      int4v bv = *(const int4v*)(WbT + (size_t)(16 * n + lr) * 256 + k0 + lk);
      bf16x8 bf = __builtin_bit_cast(bf16x8, bv);
      acc[n] = __builtin_amdgcn_mfma_f32_16x16x32_bf16(af, bf, acc[n], 0, 0, 0);
    }
  }

  float sp[4] = {0.f, 0.f, 0.f, 0.f}, dp[4] = {0.f, 0.f, 0.f, 0.f};
#pragma unroll
  for (int n = 0; n < 16; ++n) {
    int col = 16 * n + lr;
    float as = a[col];
    float ad = a[256 + col];
#pragma unroll
    for (int rr = 0; rr < 4; ++rr) {
      int row = bid * 64 + 16 * w + ((l >> 4) << 2) + rr;
      int bb = row >> 12, kk = row & 4095;
      float v = acc[n][rr];
      size_t addr = (size_t)bb * 1048576 + (size_t)(kk >> 5) * 8192 +
                    (col >> 4) * 512 + ((kk >> 3) & 3) * 128 + (col & 15) * 8 +
                    (kk & 7);
      HhTt[addr] = f2bf(v);
      sp[rr] += v * as;
      dp[rr] += v * ad;
    }
  }
#pragma unroll
  for (int rr = 0; rr < 4; ++rr) {
#pragma unroll
    for (int off = 1; off < 16; off <<= 1) {
      sp[rr] += __shfl_xor(sp[rr], off);
      dp[rr] += __shfl_xor(dp[rr], off);
    }
  }
  if ((l & 15) == 0) {
#pragma unroll
    for (int rr = 0; rr < 4; ++rr) {
      int row = bid * 64 + 16 * w + ((l >> 4) << 2) + rr;
      sbuf[row] = sp[rr];
      dbuf[row] = dp[rr];
    }
  }
}

// ---------------- kernel 3: main fused GAT aggregation ----------------
// grid 512 (2/CU), 256 thr / 4 waves; BM=64 rows x BN=128 cols per block
// (column-split: 2 blocks per row-panel). Wave grid 2x2 (32 rows x 64 cols).
// Per step: 8KB B-tile via 2 DMAs/wave, 1 D DMA/wave -> vmcnt(3) cadence.
// Mask panel (32KB) LDS-resident; e-gen 1 step ahead into 2-buf At.
__global__ __launch_bounds__(256, 2) void gat_main(const u32* __restrict__ maskg,
                                                   const u16* __restrict__ HhTt,
                                                   const float* __restrict__ s,
                                                   const float* __restrict__ d,
                                                   float* __restrict__ out) {
  __shared__ __align__(16) u16 Bt[3][4096];    // 24 KB: [buf][8KB tile]
  __shared__ __align__(16) u16 At[2][2048];    // 8 KB: [buf][row64][k32]
  __shared__ __align__(16) u32 Mk[8192];       // 32 KB rotated mask panel
  __shared__ __align__(16) float Dt[3][32];    // 384 B
  __shared__ float rs_lds[64];

  const int tid = threadIdx.x, bid = blockIdx.x;
  const int xcd = bid & 7;
  const int t = ((xcd & 1) << 6) | (bid >> 3);   // 0..127
  const int b = xcd >> 1;
  const int rowpanel = t >> 1, ch = t & 1;
  const int rowbase = rowpanel << 6;

  const int l = tid & 63, w = tid >> 6;
  const int lr = l & 15, lkg = l >> 4;
  const int wr = w & 1, wc = w >> 1;
  const int er = tid >> 2, c4 = tid & 3;         // e-gen: row er, 8-bit group c4

  // ---- mask panel load (rotated -> conflict-free per-step reads) ----
  {
    const u32* mrow = maskg + ((size_t)(b * 4096 + rowbase)) * 128;
    const int r = tid >> 2;
    const int w0 = (tid & 3) * 32;
#pragma unroll
    for (int j = 0; j < 32; ++j) {
      int ww = w0 + j;
      Mk[r * 128 + ((ww + r) & 127)] = mrow[r * 128 + ww];
    }
  }

  const float s_e = s[b * 4096 + rowbase + er];

  // ---- DMA sources ----
  const char* bsrcB = (const char*)HhTt + (size_t)b * 2097152 + ch * 8192 + l * 16;
  const char* dsrcB = (const char*)d + (size_t)b * 16384 + w * 32 + l * 16;
  char* BtB = (char*)&Bt[0][0];
  char* DtB = (char*)&Dt[0][0];

  // ---- LDS read offsets (u16 units; R6-verified) ----
  const int atoff0 = (32 * wr + lr) * 32 + lkg * 8;
  const int atoff1 = (32 * wr + 16 + lr) * 32 + lkg * 8;
  const int btbase = 4 * wc * 512 + lkg * 128 + lr * 8;

  f32x4 acc0[4], acc1[4];
#pragma unroll
  for (int n = 0; n < 4; ++n) {
    acc0[n] = (f32x4){0.f, 0.f, 0.f, 0.f};
    acc1[n] = (f32x4){0.f, 0.f, 0.f, 0.f};
  }
  float racc = 0.f;

#define ISSUE_B(BUF, STEP)                                                    \
  {                                                                           \
    const size_t so_ = (size_t)(STEP) * 16384;                                \
    gload16(bsrcB + so_ + (w * 2 + 0) * 1024,                                 \
            BtB + (BUF) * 8192 + (w * 2 + 0) * 1024);                         \
    gload16(bsrcB + so_ + (w * 2 + 1) * 1024,                                 \
            BtB + (BUF) * 8192 + (w * 2 + 1) * 1024);                         \
  }

#define ISSUE_D(STEP)                                                         \
  {                                                                           \
    const int dst_ = (STEP) > 127 ? 127 : (STEP);                             \
    if (l < 2) gload16(dsrcB + (size_t)dst_ * 128,                            \
                       DtB + (dst_ % 3) * 128 + w * 32 + l * 16);             \
  }

#define EGEN(BA, STEP)                                                        \
  {                                                                           \
    u32 mword = Mk[er * 128 + (((STEP) + er) & 127)];                         \
    u32 m8 = mword >> (c4 * 8);                                               \
    f32x4 dvA = *(const f32x4*)(DtB + ((STEP) % 3) * 128 + c4 * 32);          \
    f32x4 dvB = *(const f32x4*)(DtB + ((STEP) % 3) * 128 + c4 * 32 + 16);     \
    u16x8 ev;                                                                 \
    _Pragma("unroll")                                                         \
    for (int j = 0; j < 8; ++j) {                                             \
      float lg = s_e + (j < 4 ? dvA[j & 3] : dvB[j & 3]);                     \
      float tt = fmaxf(lg, LRELU_ALPHA * lg);                                 \
      float e = ((m8 >> j) & 1) ? __expf(-tt) : 0.f;                          \
      racc += e;                                                              \
      ev[j] = f2bf(e);                                                        \
    }                                                                         \
    *(int4v*)&At[BA][er * 32 + c4 * 8] = __builtin_bit_cast(int4v, ev);       \
  }

#define COMPUTE(BB, BA)                                                       \
  {                                                                           \
    bf16x8 af0 = __builtin_bit_cast(bf16x8, *(const int4v*)&At[BA][atoff0]);  \
    bf16x8 af1 = __builtin_bit_cast(bf16x8, *(const int4v*)&At[BA][atoff1]);  \
    __builtin_amdgcn_s_setprio(1);                                            \
    _Pragma("unroll")                                                         \
    for (int n = 0; n < 4; ++n) {                                             \
      bf16x8 bfv = __builtin_bit_cast(bf16x8,                                 \
          *(const int4v*)&Bt[BB][btbase + n * 512]);                          \
      acc0[n] = __builtin_amdgcn_mfma_f32_16x16x32_bf16(af0, bfv, acc0[n],    \
                                                        0, 0, 0);             \
      acc1[n] = __builtin_amdgcn_mfma_f32_16x16x32_bf16(af1, bfv, acc1[n],    \
                                                        0, 0, 0);             \
    }                                                                         \
    __builtin_amdgcn_s_setprio(0);                                            \
  }

// step J: issue B(J+2) (2 DMA) + D(J+3) (1 DMA); e-gen J+1; compute J;
// vmcnt(3) completes B(J+1)x2 + D(J+2), leaving [B(J+2)x2, D(J+3)].
#define SUBSTEP(J, BB, BA, BI, BAN)                                           \
  {                                                                           \
    ISSUE_B(BI, (J) + 2)                                                      \
    ISSUE_D((J) + 3)                                                          \
    EGEN(BAN, (J) + 1)                                                        \
    COMPUTE(BB, BA)                                                           \
    asm volatile("s_waitcnt lgkmcnt(0)" ::: "memory");                        \
    asm volatile("s_waitcnt vmcnt(3)" ::: "memory");                          \
    __builtin_amdgcn_s_barrier();                                             \
  }

  // ---- prologue ----
  ISSUE_B(0, 0)
  ISSUE_B(1, 1)
  ISSUE_D(1)
  ISSUE_D(2)
  f32x4 d0A = *(const f32x4*)(d + b * 4096 + c4 * 8);
  f32x4 d0B = *(const f32x4*)(d + b * 4096 + c4 * 8 + 4);
  __syncthreads();   // Mk visible; drains prologue DMAs (once)
  {
    u32 mword = Mk[er * 128 + (er & 127)];
    u32 m8 = mword >> (c4 * 8);
    u16x8 ev;
#pragma unroll
    for (int j = 0; j < 8; ++j) {
      float lg = s_e + (j < 4 ? d0A[j & 3] : d0B[j & 3]);
      float tt = fmaxf(lg, LRELU_ALPHA * lg);
      float e = ((m8 >> j) & 1) ? __expf(-tt) : 0.f;
      racc += e;
      ev[j] = f2bf(e);
    }
    *(int4v*)&At[0][er * 32 + c4 * 8] = __builtin_bit_cast(int4v, ev);
  }
  asm volatile("s_waitcnt lgkmcnt(0)" ::: "memory");
  __builtin_amdgcn_s_barrier();

  for (int k = 0; k < 126; k += 6) {
    SUBSTEP(k + 0, 0, 0, 2, 1)
    SUBSTEP(k + 1, 1, 1, 0, 0)
    SUBSTEP(k + 2, 2, 0, 1, 1)
    SUBSTEP(k + 3, 0, 1, 2, 0)
    SUBSTEP(k + 4, 1, 0, 0, 1)
    SUBSTEP(k + 5, 2, 1, 1, 0)
  }
  // tail: J=126 (no issues), J=127
  EGEN(1, 127)
  COMPUTE(0, 0)
  asm volatile("s_waitcnt lgkmcnt(0)" ::: "memory");
  asm volatile("s_waitcnt vmcnt(0)" ::: "memory");
  __builtin_amdgcn_s_barrier();
  COMPUTE(1, 1)
#undef ISSUE_B
#undef ISSUE_D
#undef EGEN
#undef COMPUTE
#undef SUBSTEP

  // ---- rowsum: reduce the 4 c4-partials of each row ----
  racc += __shfl_xor(racc, 1);
  racc += __shfl_xor(racc, 2);
  if (c4 == 0) rs_lds[er] = (racc == 0.f) ? 1.f : racc;
  __syncthreads();

  // ---- epilogue: divide + elu + store ----
#pragma unroll
  for (int t16 = 0; t16 < 2; ++t16) {
#pragma unroll
    for (int n = 0; n < 4; ++n) {
#pragma unroll
      for (int reg = 0; reg < 4; ++reg) {
        int rloc = 32 * wr + 16 * t16 + lkg * 4 + reg;
        int col = ch * 128 + wc * 64 + 16 * n + lr;
        float v = (t16 ? acc1[n][reg] : acc0[n][reg]) / rs_lds[rloc];
        out[((size_t)(b * 4096 + rowbase + rloc)) * 256 + col] =
            v > 0.f ? v : (__expf(v) - 1.f);
      }
    }
  }
}

extern "C" void kernel_launch(void* const* d_in, const int* in_sizes, int n_in,
                              void* d_out, int out_size, void* d_ws, size_t ws_size,
                              hipStream_t stream) {
  const float* h = (const float*)d_in[0];
  const int* adj = (const int*)d_in[1];
  const float* W = (const float*)d_in[2];
  const float* a = (const float*)d_in[3];
  float* out = (float*)d_out;

  u16* WbT   = (u16*)d_ws;                                       // 128 KB
  u16* HhTt  = (u16*)((char*)d_ws + 131072);                     // 8 MB
  float* sb  = (float*)((char*)d_ws + 131072 + 8388608);         // 64 KB
  float* db  = sb + 16384;                                       // 64 KB
  u32* maskg = (u32*)((char*)d_ws + 131072 + 8388608 + 131072);  // 8 MB

  hipLaunchKernelGGL(packw,    dim3(4352), dim3(256), 0, stream, adj, maskg, W, WbT);
  hipLaunchKernelGGL(gemm1,    dim3(256),  dim3(256), 0, stream, h, WbT, a, HhTt, sb, db);
  hipLaunchKernelGGL(gat_main, dim3(512),  dim3(256), 0, stream, maskg, HhTt, sb, db, out);
}

// Round 9
// 171.996 us; speedup vs baseline: 1.0111x; 1.0111x over previous
//
#include <hip/hip_runtime.h>

#define LRELU_ALPHA 0.2f

typedef __bf16 bf16x8 __attribute__((ext_vector_type(8)));
typedef unsigned short u16;
typedef unsigned short u16x8 __attribute__((ext_vector_type(8)));
typedef float f32x4 __attribute__((ext_vector_type(4)));
typedef int int4v __attribute__((ext_vector_type(4)));
typedef unsigned int u32;
typedef unsigned int u32x4 __attribute__((ext_vector_type(4)));
typedef unsigned long long u64;

__device__ __forceinline__ u16 f2bf(float f) {
  unsigned int u = __float_as_uint(f);
  u += 0x7fffu + ((u >> 16) & 1u);   // RNE
  return (u16)(u >> 16);
}

// ------- kernel 1: packadj (blocks 0..4095) + wcast (blocks 4096..4351) ----
__global__ __launch_bounds__(256) void packw(const int* __restrict__ adj,
                                             u32* __restrict__ maskg,
                                             const float* __restrict__ W,
                                             u16* __restrict__ WbT) {
  const int tid = threadIdx.x;
  if (blockIdx.x >= 4096) {
    int idx = (blockIdx.x - 4096) * 256 + tid;        // 65536
    WbT[idx] = f2bf(W[(idx & 255) * 256 + (idx >> 8)]);
    return;
  }
  const int l = tid & 63, w = tid >> 6;
  const size_t row = (size_t)blockIdx.x * 4 + w;
  const int* arow = adj + row * 4096;
  u64* mrow = (u64*)(maskg + row * 128);
  for (int it = 0; it < 16; ++it) {
    const int* base = arow + it * 256;
    int v0 = base[l], v1 = base[l + 64], v2 = base[l + 128], v3 = base[l + 192];
    u64 b0 = __ballot(v0 != 0);
    u64 b1 = __ballot(v1 != 0);
    u64 b2 = __ballot(v2 != 0);
    u64 b3 = __ballot(v3 != 0);
    if (l == 0) {
      mrow[it * 4 + 0] = b0;
      mrow[it * 4 + 1] = b1;
      mrow[it * 4 + 2] = b2;
      mrow[it * 4 + 3] = b3;
    }
  }
}

// ---------------- kernel 2: Hh = bf16(h) @ W, fused s/d dots ----------
// HhTt tiled layout (u16 index):
// b*1048576 + (k>>5)*8192 + (col>>4)*512 + ((k>>3)&3)*128 + (col&15)*8 + (k&7)
__global__ __launch_bounds__(256) void gemm1(const float* __restrict__ h,
                                             const u16* __restrict__ WbT,
                                             const float* __restrict__ a,
                                             u16* __restrict__ HhTt,
                                             float* __restrict__ sbuf,
                                             float* __restrict__ dbuf) {
  const int tid = threadIdx.x, bid = blockIdx.x;
  const int l = tid & 63, w = tid >> 6;
  const int lr = l & 15;
  const int lk = (l >> 4) << 3;
  const int rowA = bid * 64 + 16 * w + lr;
  const float* hrow = h + (size_t)rowA * 256 + lk;

  f32x4 acc[16];
#pragma unroll
  for (int n = 0; n < 16; ++n) acc[n] = (f32x4){0.f, 0.f, 0.f, 0.f};

  for (int k0 = 0; k0 < 256; k0 += 32) {
    f32x4 a0 = *(const f32x4*)(hrow + k0);
    f32x4 a1 = *(const f32x4*)(hrow + k0 + 4);
    u16x8 au;
    au[0] = f2bf(a0[0]); au[1] = f2bf(a0[1]); au[2] = f2bf(a0[2]); au[3] = f2bf(a0[3]);
    au[4] = f2bf(a1[0]); au[5] = f2bf(a1[1]); au[6] = f2bf(a1[2]); au[7] = f2bf(a1[3]);
    bf16x8 af = __builtin_bit_cast(bf16x8, au);
#pragma unroll
    for (int n = 0; n < 16; ++n) {
      int4v bv = *(const int4v*)(WbT + (size_t)(16 * n + lr) * 256 + k0 + lk);
      bf16x8 bf = __builtin_bit_cast(bf16x8, bv);
      acc[n] = __builtin_amdgcn_mfma_f32_16x16x32_bf16(af, bf, acc[n], 0, 0, 0);
    }
  }

  float sp[4] = {0.f, 0.f, 0.f, 0.f}, dp[4] = {0.f, 0.f, 0.f, 0.f};
#pragma unroll
  for (int n = 0; n < 16; ++n) {
    int col = 16 * n + lr;
    float as = a[col];
    float ad = a[256 + col];
#pragma unroll
    for (int rr = 0; rr < 4; ++rr) {
      int row = bid * 64 + 16 * w + ((l >> 4) << 2) + rr;
      int bb = row >> 12, kk = row & 4095;
      float v = acc[n][rr];
      size_t addr = (size_t)bb * 1048576 + (size_t)(kk >> 5) * 8192 +
                    (col >> 4) * 512 + ((kk >> 3) & 3) * 128 + (col & 15) * 8 +
                    (kk & 7);
      HhTt[addr] = f2bf(v);
      sp[rr] += v * as;
      dp[rr] += v * ad;
    }
  }
#pragma unroll
  for (int rr = 0; rr < 4; ++rr) {
#pragma unroll
    for (int off = 1; off < 16; off <<= 1) {
      sp[rr] += __shfl_xor(sp[rr], off);
      dp[rr] += __shfl_xor(dp[rr], off);
    }
  }
  if ((l & 15) == 0) {
#pragma unroll
    for (int rr = 0; rr < 4; ++rr) {
      int row = bid * 64 + 16 * w + ((l >> 4) << 2) + rr;
      sbuf[row] = sp[rr];
      dbuf[row] = dp[rr];
    }
  }
}

// ---------------- kernel 3: main fused GAT aggregation ----------------
// grid 512 (2/CU), 256 thr / 4 waves; BM=32 rows x BN=256 cols per block.
// NO barriers / NO DMA in the K-loop: A-fragments (e) generated in
// registers from LDS-resident mask+d; B-fragments loaded directly from
// L2-resident HhTt (1KB contiguous per wave-load). Waves free-run.
__global__ __launch_bounds__(256, 2) void gat_main(const u32* __restrict__ maskg,
                                                   const u16* __restrict__ HhTt,
                                                   const float* __restrict__ s,
                                                   const float* __restrict__ d,
                                                   float* __restrict__ out) {
  __shared__ __align__(16) u32 Mk[32 * 128];   // 16 KB rotated mask panel
  __shared__ __align__(16) float Dl[4096];     // 16 KB

  const int tid = threadIdx.x, bid = blockIdx.x;
  const int xcd = bid & 7;
  const int t = (xcd << 6) | (bid >> 3);       // 0..511 bijective
  const int b = t >> 7;                        // batch -> XCD pair
  const int rowbase = (t & 127) << 5;

  const int l = tid & 63, w = tid >> 6;
  const int lr = l & 15, lkg = l >> 4;
  const int wr = w & 1, wc = w >> 1;           // 2 row-halves x 2 col-halves
  const int rowl = wr * 16 + lr;               // local row 0..31

  // ---- prologue: stage d (16KB) + rotated mask panel (16KB) ----
  for (int i = tid; i < 1024; i += 256)
    *(f32x4*)&Dl[i * 4] = *(const f32x4*)(d + b * 4096 + i * 4);
  {
    const u32* mrow = maskg + ((size_t)(b * 4096 + rowbase)) * 128;
    const int r = tid >> 3, c0 = (tid & 7) * 16;
#pragma unroll
    for (int j = 0; j < 16; ++j) {
      int c = c0 + j;
      Mk[r * 128 + ((c + r) & 127)] = mrow[r * 128 + c];
    }
  }
  const float s_row = s[b * 4096 + rowbase + rowl];
  __syncthreads();   // the only block-wide barrier

  // B source: tiled layout, this lane's 16B chunk of col-group (wc*8+n)
  const char* bsrc = (const char*)HhTt +
      ((size_t)b * 1048576 + (wc * 8) * 512 + lkg * 128 + lr * 8) * 2;

  f32x4 acc[8];
#pragma unroll
  for (int n = 0; n < 8; ++n) acc[n] = (f32x4){0.f, 0.f, 0.f, 0.f};
  float racc = 0.f;
  const int mkbase = rowl * 128;

  for (int step = 0; step < 128; ++step) {
    const char* bs = bsrc + (size_t)step * 16384;
    int4v bv[8];
#pragma unroll
    for (int n = 0; n < 8; ++n) bv[n] = *(const int4v*)(bs + n * 1024);

    // ---- e-gen: 8 values for (row rowl, k = step*32 + lkg*8 + j) ----
    u32 mword = Mk[mkbase + ((step + rowl) & 127)];
    u32 m8 = mword >> (lkg * 8);
    f32x4 dA = *(const f32x4*)&Dl[step * 32 + lkg * 8];
    f32x4 dB = *(const f32x4*)&Dl[step * 32 + lkg * 8 + 4];
    float ev[8];
#pragma unroll
    for (int j = 0; j < 8; ++j) {
      float lg = s_row + (j < 4 ? dA[j & 3] : dB[j & 3]);
      float tt = fmaxf(lg, LRELU_ALPHA * lg);
      float e = ((m8 >> j) & 1) ? __expf(-tt) : 0.f;
      racc += e;
      ev[j] = e;
    }
    u32x4 pk;
    asm("v_cvt_pk_bf16_f32 %0, %1, %2" : "=v"(pk[0]) : "v"(ev[0]), "v"(ev[1]));
    asm("v_cvt_pk_bf16_f32 %0, %1, %2" : "=v"(pk[1]) : "v"(ev[2]), "v"(ev[3]));
    asm("v_cvt_pk_bf16_f32 %0, %1, %2" : "=v"(pk[2]) : "v"(ev[4]), "v"(ev[5]));
    asm("v_cvt_pk_bf16_f32 %0, %1, %2" : "=v"(pk[3]) : "v"(ev[6]), "v"(ev[7]));
    bf16x8 af = __builtin_bit_cast(bf16x8, pk);

#pragma unroll
    for (int n = 0; n < 8; ++n) {
      bf16x8 bfv = __builtin_bit_cast(bf16x8, bv[n]);
      acc[n] = __builtin_amdgcn_mfma_f32_16x16x32_bf16(af, bfv, acc[n], 0, 0, 0);
    }
  }

  // ---- rowsum: combine lkg partials; distribute via shfl (no LDS) ----
  racc += __shfl_xor(racc, 16);
  racc += __shfl_xor(racc, 32);
  // lane lr now holds rowsum(row wr*16 + lr)
  float inv[4];
#pragma unroll
  for (int reg = 0; reg < 4; ++reg) {
    float rsv = __shfl(racc, lkg * 4 + reg);
    inv[reg] = 1.f / (rsv == 0.f ? 1.f : rsv);
  }

  // ---- epilogue: divide + elu + store ----
  const size_t obase =
      ((size_t)(b * 4096 + rowbase + wr * 16 + lkg * 4)) * 256 + wc * 128;
#pragma unroll
  for (int n = 0; n < 8; ++n) {
#pragma unroll
    for (int reg = 0; reg < 4; ++reg) {
      float v = acc[n][reg] * inv[reg];
      out[obase + (size_t)reg * 256 + 16 * n + lr] =
          v > 0.f ? v : (__expf(v) - 1.f);
    }
  }
}

extern "C" void kernel_launch(void* const* d_in, const int* in_sizes, int n_in,
                              void* d_out, int out_size, void* d_ws, size_t ws_size,
                              hipStream_t stream) {
  const float* h = (const float*)d_in[0];
  const int* adj = (const int*)d_in[1];
  const float* W = (const float*)d_in[2];
  const float* a = (const float*)d_in[3];
  float* out = (float*)d_out;

  u16* WbT   = (u16*)d_ws;                                       // 128 KB
  u16* HhTt  = (u16*)((char*)d_ws + 131072);                     // 8 MB
  float* sb  = (float*)((char*)d_ws + 131072 + 8388608);         // 64 KB
  float* db  = sb + 16384;                                       // 64 KB
  u32* maskg = (u32*)((char*)d_ws + 131072 + 8388608 + 131072);  // 8 MB

  hipLaunchKernelGGL(packw,    dim3(4352), dim3(256), 0, stream, adj, maskg, W, WbT);
  hipLaunchKernelGGL(gemm1,    dim3(256),  dim3(256), 0, stream, h, WbT, a, HhTt, sb, db);
  hipLaunchKernelGGL(gat_main, dim3(512),  dim3(256), 0, stream, maskg, HhTt, sb, db, out);
}